// Round 7
// baseline (230.409 us; speedup 1.0000x reference)
//
#include <hip/hip_runtime.h>
#include <hip/hip_bf16.h>

// Problem: B=8, S=1024, EMBED=1024, DK=DV=512, M=64. Inputs/outputs f32.
// Identity: landmark selection is a segment permutation P of k, so
// kernel_1 = K3 P^T, pinv(kernel_2) = P pinv(K3), and
// out = K3 K3+ K3 v = K3 v == softmax(q k^T) v  (standard attention).
#define SS   1024
#define DKK  512

typedef __hip_bfloat16 bf16;
typedef __attribute__((ext_vector_type(8))) short s16x8;            // 8 x bf16
typedef __attribute__((ext_vector_type(8))) unsigned short u16x8;
typedef __attribute__((ext_vector_type(4))) float f32x4;

// ---- ws layout (byte offsets), 76 MiB ----
// P' 16 MiB at 0; stats 2 MiB at 40 MiB; W(z) bf16 1 MiB at 48+z MiB;
// q 52 MiB; k 60 MiB; vT 68 MiB.
#define WS_ST    (40ull << 20)
#define WS_W(z)  ((48ull << 20) + ((size_t)(z) << 20))
#define WS_Q     (52ull << 20)
#define WS_K     (60ull << 20)
#define WS_VT    (68ull << 20)
#define WS_LG    (0ull)

__device__ __forceinline__ void async_ld16(const void* g, void* s) {
  __builtin_amdgcn_global_load_lds(
      (const __attribute__((address_space(1))) void*)g,
      (__attribute__((address_space(3))) void*)s, 16, 0, 0);
}

__device__ __forceinline__ unsigned short f2bfu(float f) {
  return __builtin_bit_cast(unsigned short, __float2bfloat16(f));
}
__device__ __forceinline__ float bfu2f(unsigned short u) {
  unsigned int i = ((unsigned int)u) << 16;
  return __builtin_bit_cast(float, i);
}

// Convert the 3 weight tensors (512K elems each) f32 -> bf16 into ws.
__global__ __launch_bounds__(256)
void convert_w(const float* __restrict__ w0, const float* __restrict__ w1,
               const float* __restrict__ w2, char* __restrict__ ws)
{
  const int bx = blockIdx.x;
  const int z = bx >> 8, local = bx & 255;
  const float* src = (z == 0) ? w0 : (z == 1) ? w1 : w2;
  unsigned short* dst = (unsigned short*)(ws + WS_W(z));
  const int i = local * 2048 + threadIdx.x * 8;
  const float4* s = (const float4*)(src + i);
  float4 a = s[0], b = s[1];
  ushort4 o0, o1;
  o0.x = f2bfu(a.x); o0.y = f2bfu(a.y); o0.z = f2bfu(a.z); o0.w = f2bfu(a.w);
  o1.x = f2bfu(b.x); o1.y = f2bfu(b.y); o1.z = f2bfu(b.z); o1.w = f2bfu(b.w);
  ((ushort4*)(dst + i))[0] = o0;
  ((ushort4*)(dst + i))[1] = o1;
}

// ---------- bf16 x bf16 core ----------
// C[BM x BN] = A[BM x K] * B[BN x K]^T, both K-contiguous bf16.
// LDS via global_load_lds w=16; LDS[row][slot] holds chunk (slot ^ (row&7)).
template<int BM, int BN, int K, int LDA, int LDB>
__device__ __forceinline__ void gemm_core(const bf16* __restrict__ A,
                                          const bf16* __restrict__ Bw,
                                          int bm, int bn,
                                          short* As, short* Bs, f32x4* acc)
{
  constexpr int MI = BM / 32, NI = BN / 32;
  constexpr int AR = BM / 4,  BR = BN / 4;
  const int tid  = threadIdx.x;
  const int lane = tid & 63;
  const int wave = tid >> 6;
  const int l8   = lane >> 3;
  const int kch  = ((lane & 7) ^ l8) * 8;
  const bf16* ag = A  + (size_t)(bm * BM + wave * AR + l8) * LDA + kch;
  const bf16* bg = Bw + (size_t)(bn * BN + wave * BR + l8) * LDB + kch;
  short* AsW = As + wave * AR * 64;
  short* BsW = Bs + wave * BR * 64;
  const int waveM = wave >> 1, waveN = wave & 1;
  const int l16  = lane & 15;
  const int quad = lane >> 4;
  const int xr   = l16 & 7;

  #pragma unroll
  for (int t = 0; t < MI * NI; ++t)
    #pragma unroll
    for (int r = 0; r < 4; ++r) acc[t][r] = 0.0f;

  for (int kt = 0; kt < K / 64; ++kt) {
    #pragma unroll
    for (int j = 0; j < AR / 8; ++j) async_ld16(ag + (size_t)j * 8 * LDA, AsW + j * 8 * 64);
    #pragma unroll
    for (int j = 0; j < BR / 8; ++j) async_ld16(bg + (size_t)j * 8 * LDB, BsW + j * 8 * 64);
    ag += 64; bg += 64;
    __syncthreads();
    #pragma unroll
    for (int ks = 0; ks < 2; ++ks) {
      s16x8 af[MI], bfv[NI];
      #pragma unroll
      for (int mi = 0; mi < MI; ++mi) {
        const int row  = waveM * (BM / 2) + mi * 16 + l16;
        const int slot = (ks * 4 + quad) ^ xr;
        af[mi] = *(const s16x8*)&As[row * 64 + slot * 8];
      }
      #pragma unroll
      for (int ni = 0; ni < NI; ++ni) {
        const int row  = waveN * (BN / 2) + ni * 16 + l16;
        const int slot = (ks * 4 + quad) ^ xr;
        bfv[ni] = *(const s16x8*)&Bs[row * 64 + slot * 8];
      }
      #pragma unroll
      for (int mi = 0; mi < MI; ++mi)
        #pragma unroll
        for (int ni = 0; ni < NI; ++ni)
          acc[mi * NI + ni] = __builtin_amdgcn_mfma_f32_16x16x32_bf16(
              af[mi], bfv[ni], acc[mi * NI + ni], 0, 0, 0);
    }
    __syncthreads();
  }
}

// ---------- f32-A x bf16-B core for proj: BM=64, BN=256 ----------
// A f32 via reg round-trip + inline cvt into swizzled LDS, PREFETCHED one
// kt ahead so the global-load latency overlaps the MFMA loop.
template<int K, int LDA, int LDB>
__device__ __forceinline__ void gemm_core_f32a(const float* __restrict__ A,
                                               const bf16* __restrict__ Bw,
                                               int bm, int bn,
                                               short* As, short* Bs, f32x4* acc)
{
  const int tid  = threadIdx.x;
  const int lane = tid & 63;
  const int wave = tid >> 6;
  const int l8   = lane >> 3;
  const int kch  = ((lane & 7) ^ l8) * 8;
  const bf16* bg = Bw + (size_t)(bn * 256 + wave * 64 + l8) * LDB + kch;
  short* BsW = Bs + wave * 64 * 64;
  const int arow = tid >> 3;
  const int ag8  = tid & 7;
  const int slotA = (ag8 ^ (arow & 7)) * 8;
  const float* agp = A + (size_t)(bm * 64 + arow) * LDA + ag8 * 8;
  const int waveM = wave >> 1, waveN = wave & 1;
  const int l16  = lane & 15;
  const int quad = lane >> 4;
  const int xr   = l16 & 7;

  #pragma unroll
  for (int t = 0; t < 16; ++t)
    #pragma unroll
    for (int r = 0; r < 4; ++r) acc[t][r] = 0.0f;

  float4 a0 = ((const float4*)agp)[0], b0 = ((const float4*)agp)[1];
  float4 a1 = ((const float4*)(agp + 32 * LDA))[0];
  float4 b1 = ((const float4*)(agp + 32 * LDA))[1];
  agp += 64;

  for (int kt = 0; kt < K / 64; ++kt) {
    #pragma unroll
    for (int j = 0; j < 8; ++j) async_ld16(bg + (size_t)j * 8 * LDB, BsW + j * 8 * 64);
    bg += 64;
    u16x8 v0, v1;
    v0[0] = f2bfu(a0.x); v0[1] = f2bfu(a0.y); v0[2] = f2bfu(a0.z); v0[3] = f2bfu(a0.w);
    v0[4] = f2bfu(b0.x); v0[5] = f2bfu(b0.y); v0[6] = f2bfu(b0.z); v0[7] = f2bfu(b0.w);
    v1[0] = f2bfu(a1.x); v1[1] = f2bfu(a1.y); v1[2] = f2bfu(a1.z); v1[3] = f2bfu(a1.w);
    v1[4] = f2bfu(b1.x); v1[5] = f2bfu(b1.y); v1[6] = f2bfu(b1.z); v1[7] = f2bfu(b1.w);
    *(u16x8*)&As[arow * 64 + slotA] = v0;
    *(u16x8*)&As[(32 + arow) * 64 + slotA] = v1;
    if (kt != K / 64 - 1) {
      a0 = ((const float4*)agp)[0]; b0 = ((const float4*)agp)[1];
      a1 = ((const float4*)(agp + 32 * LDA))[0];
      b1 = ((const float4*)(agp + 32 * LDA))[1];
    }
    agp += 64;
    __syncthreads();
    #pragma unroll
    for (int ks = 0; ks < 2; ++ks) {
      s16x8 af[2], bfv[8];
      #pragma unroll
      for (int mi = 0; mi < 2; ++mi) {
        const int row  = waveM * 32 + mi * 16 + l16;
        const int slot = (ks * 4 + quad) ^ xr;
        af[mi] = *(const s16x8*)&As[row * 64 + slot * 8];
      }
      #pragma unroll
      for (int ni = 0; ni < 8; ++ni) {
        const int row  = waveN * 128 + ni * 16 + l16;
        const int slot = (ks * 4 + quad) ^ xr;
        bfv[ni] = *(const s16x8*)&Bs[row * 64 + slot * 8];
      }
      #pragma unroll
      for (int mi = 0; mi < 2; ++mi)
        #pragma unroll
        for (int ni = 0; ni < 8; ++ni)
          acc[mi * 8 + ni] = __builtin_amdgcn_mfma_f32_16x16x32_bf16(
              af[mi], bfv[ni], acc[mi * 8 + ni], 0, 0, 0);
    }
    __syncthreads();
  }
}

// z=0: q = (Xq Wq^T + bq) * 512^-0.5 ; z=1: k = Xk Wk^T + bk ;
// z=2: vT[b][d][s] = (Xv Wv^T + bv)^T.
// Flat 768-block grid; bn-siblings of each (bm,z) panel land on one XCD.
__global__ __launch_bounds__(256, 3)
void proj_kernel(const float* __restrict__ Xq, const float* __restrict__ Xk,
                 const float* __restrict__ Xv, const bf16* __restrict__ W0,
                 const float* __restrict__ bq, const float* __restrict__ bk,
                 const float* __restrict__ bv,
                 bf16* __restrict__ qo, bf16* __restrict__ ko,
                 bf16* __restrict__ vT, float qscale)
{
  __shared__ __align__(16) short As[64 * 64];
  __shared__ __align__(16) short Bs[256 * 64];
  const int id   = blockIdx.x;
  const int xcd  = id & 7;
  const int s    = id >> 3;            // 0..95
  const int bn   = s & 1;
  const int pair = (s >> 1) * 8 + xcd; // 0..383 unique
  const int bm   = pair & 127;
  const int z    = pair >> 7;          // 0..2
  const float* A  = (z == 0) ? Xq : (z == 1) ? Xk : Xv;
  const bf16*  Bw = W0 + ((size_t)z << 19);
  const float* bias = (z == 0) ? bq : (z == 1) ? bk : bv;
  f32x4 acc[16];
  gemm_core_f32a<1024, 1024, 1024>(A, Bw, bm, bn, As, Bs, acc);

  const int lane = threadIdx.x & 63;
  const int wave = threadIdx.x >> 6;
  const int waveM = wave >> 1, waveN = wave & 1;
  const int l16 = lane & 15, quad = lane >> 4;
  const int row0 = bm * 64 + waveM * 32;
  const int col0 = bn * 256 + waveN * 128;
  const float sc = (z == 0) ? qscale : 1.0f;
  bf16* C = (z == 0) ? qo : ko;
  #pragma unroll
  for (int ni = 0; ni < 8; ++ni) {
    const int col = col0 + ni * 16 + l16;
    const float bb = bias[col];
    #pragma unroll
    for (int mi = 0; mi < 2; ++mi)
      #pragma unroll
      for (int r = 0; r < 4; ++r) {
        const int row = row0 + mi * 16 + quad * 4 + r;
        const float v = acc[mi * 8 + ni][r] + bb;
        if (z == 2)
          vT[((size_t)(row >> 10) * DKK + col) * SS + (row & (SS - 1))] =
              __float2bfloat16(v);
        else
          C[(size_t)row * DKK + col] = __float2bfloat16(v * sc);
      }
  }
}

// scores: P'[b][s][t] = exp(x - m_chunk) (bf16) where x = q.k, plus per-
// (row, 32-col-chunk) stats (m, sum) in f32. BM=BN=64, grid (16,16,8)=2048.
__global__ __launch_bounds__(256, 8)
void scores_kernel(const bf16* __restrict__ q, const bf16* __restrict__ k,
                   unsigned short* __restrict__ Pp, float* __restrict__ stats)
{
  __shared__ __align__(16) short As[64 * 64];
  __shared__ __align__(16) short Bs[64 * 64];
  const int z = blockIdx.z;
  const int bn = blockIdx.x, bm = blockIdx.y;
  f32x4 acc[4];
  gemm_core<64, 64, 512, 512, 512>(q + (size_t)z * SS * DKK,
                                   k + (size_t)z * SS * DKK,
                                   bm, bn, As, Bs, acc);

  const int lane = threadIdx.x & 63;
  const int wave = threadIdx.x >> 6;
  const int waveM = wave >> 1, waveN = wave & 1;
  const int l16 = lane & 15, quad = lane >> 4;
  const int row0 = bm * 64 + waveM * 32;
  const int col0 = bn * 64 + waveN * 32;
  const int chunk = bn * 2 + waveN;             // 32-col chunk id, 0..31
  unsigned short* C = Pp + (size_t)z * SS * SS;
  #pragma unroll
  for (int mi = 0; mi < 2; ++mi)
    #pragma unroll
    for (int r = 0; r < 4; ++r) {
      const int row = row0 + mi * 16 + quad * 4 + r;
      const float x0 = acc[mi * 2 + 0][r], x1 = acc[mi * 2 + 1][r];
      float m = fmaxf(x0, x1);
      #pragma unroll
      for (int msk = 1; msk < 16; msk <<= 1) m = fmaxf(m, __shfl_xor(m, msk));
      const float e0 = __expf(x0 - m), e1 = __expf(x1 - m);
      float ssum = e0 + e1;
      #pragma unroll
      for (int msk = 1; msk < 16; msk <<= 1) ssum += __shfl_xor(ssum, msk);
      C[(size_t)row * SS + col0 + l16]      = f2bfu(e0);
      C[(size_t)row * SS + col0 + 16 + l16] = f2bfu(e1);
      if (l16 == 0) {
        float2 mr; mr.x = m; mr.y = ssum;
        *(float2*)&stats[(((size_t)z * SS + row) * 32 + chunk) * 2] = mr;
      }
    }
}

// ---------- pv core: A = P' scaled by per-(row,chunk) factor at staging ----
__device__ __forceinline__ void gemm_core_pvs(const unsigned short* __restrict__ Pp,
                                              const bf16* __restrict__ vT,
                                              int bm, int bn, const float* Fl,
                                              short* As, short* Bs, f32x4* acc)
{
  const int tid  = threadIdx.x;
  const int lane = tid & 63;
  const int wave = tid >> 6;
  const int l8   = lane >> 3;
  const int kch  = ((lane & 7) ^ l8) * 8;
  const bf16* bg = vT + (size_t)(bn * 64 + wave * 16 + l8) * 1024 + kch;
  short* BsW = Bs + wave * 16 * 64;
  const int arow = tid >> 3;
  const int ag8  = tid & 7;
  const int slotA = (ag8 ^ (arow & 7)) * 8;
  const unsigned short* ag = Pp + (size_t)(bm * 64 + arow) * 1024 + ag8 * 8;
  const int waveM = wave >> 1, waveN = wave & 1;
  const int l16  = lane & 15;
  const int quad = lane >> 4;
  const int xr   = l16 & 7;

  #pragma unroll
  for (int t = 0; t < 4; ++t)
    #pragma unroll
    for (int r = 0; r < 4; ++r) acc[t][r] = 0.0f;

  u16x8 u0 = *(const u16x8*)ag;
  u16x8 u1 = *(const u16x8*)(ag + 32 * 1024);
  ag += 64;

  for (int kt = 0; kt < 16; ++kt) {
    #pragma unroll
    for (int j = 0; j < 2; ++j) async_ld16(bg + (size_t)j * 8 * 1024, BsW + j * 8 * 64);
    bg += 64;
    const int ch = kt * 2 + (ag8 >> 2);
    const float f0 = Fl[arow * 33 + ch];
    const float f1 = Fl[(32 + arow) * 33 + ch];
    u16x8 v0, v1;
    #pragma unroll
    for (int j = 0; j < 8; ++j) {
      v0[j] = f2bfu(bfu2f((unsigned short)u0[j]) * f0);
      v1[j] = f2bfu(bfu2f((unsigned short)u1[j]) * f1);
    }
    *(u16x8*)&As[arow * 64 + slotA] = v0;
    *(u16x8*)&As[(32 + arow) * 64 + slotA] = v1;
    if (kt != 15) {
      u0 = *(const u16x8*)ag;
      u1 = *(const u16x8*)(ag + 32 * 1024);
    }
    ag += 64;
    __syncthreads();
    #pragma unroll
    for (int ks = 0; ks < 2; ++ks) {
      s16x8 af[2], bfv[2];
      #pragma unroll
      for (int mi = 0; mi < 2; ++mi) {
        const int row  = waveM * 32 + mi * 16 + l16;
        const int slot = (ks * 4 + quad) ^ xr;
        af[mi] = *(const s16x8*)&As[row * 64 + slot * 8];
      }
      #pragma unroll
      for (int ni = 0; ni < 2; ++ni) {
        const int row  = waveN * 32 + ni * 16 + l16;
        const int slot = (ks * 4 + quad) ^ xr;
        bfv[ni] = *(const s16x8*)&Bs[row * 64 + slot * 8];
      }
      #pragma unroll
      for (int mi = 0; mi < 2; ++mi)
        #pragma unroll
        for (int ni = 0; ni < 2; ++ni)
          acc[mi * 2 + ni] = __builtin_amdgcn_mfma_f32_16x16x32_bf16(
              af[mi], bfv[ni], acc[mi * 2 + ni], 0, 0, 0);
    }
    __syncthreads();
  }
}

// out[b][s][d] = softmax(x)[b][s][:] . vT[b][d][:]; f32 out.
// grid (bn=8, bm=16, z=8) = 1024 blocks.
__global__ __launch_bounds__(256, 6)
void pv_kernel(const unsigned short* __restrict__ Pp, const bf16* __restrict__ vT,
               const float* __restrict__ stats, float* __restrict__ out)
{
  __shared__ __align__(16) short As[64 * 64];
  __shared__ __align__(16) short Bs[64 * 64];
  __shared__ float Ml[64], Rl[64], Fl[64 * 33];
  const int z = blockIdx.z;
  const int bn = blockIdx.x, bm = blockIdx.y;
  const int tid = threadIdx.x;

  if (tid < 64) {
    const float* st = stats + ((size_t)z * SS + bm * 64 + tid) * 64;
    float mc[32], lc[32];
    float M = -1e30f;
    #pragma unroll
    for (int c = 0; c < 32; ++c) {
      mc[c] = st[c * 2]; lc[c] = st[c * 2 + 1];
      M = fmaxf(M, mc[c]);
    }
    float L = 0.f;
    #pragma unroll
    for (int c = 0; c < 32; ++c) L += __expf(mc[c] - M) * lc[c];
    Ml[tid] = M; Rl[tid] = 1.0f / L;
  }
  __syncthreads();
  {
    const int row = tid >> 2, c0 = (tid & 3) * 8;
    const float* st = stats + (((size_t)z * SS + bm * 64 + row) * 32 + c0) * 2;
    const float M = Ml[row], R = Rl[row];
    #pragma unroll
    for (int j = 0; j < 8; ++j)
      Fl[row * 33 + c0 + j] = __expf(st[j * 2] - M) * R;
  }
  __syncthreads();

  f32x4 acc[4];
  gemm_core_pvs(Pp + (size_t)z * SS * SS, vT + (size_t)z * DKK * SS,
                bm, bn, Fl, As, Bs, acc);

  const int lane = tid & 63;
  const int wave = tid >> 6;
  const int waveM = wave >> 1, waveN = wave & 1;
  const int l16 = lane & 15, quad = lane >> 4;
  const int row0 = bm * 64 + waveM * 32;
  const int col0 = bn * 64 + waveN * 32;
  float* C = out + (size_t)z * SS * DKK;
  #pragma unroll
  for (int ni = 0; ni < 2; ++ni) {
    const int col = col0 + ni * 16 + l16;
    #pragma unroll
    for (int mi = 0; mi < 2; ++mi)
      #pragma unroll
      for (int r = 0; r < 4; ++r) {
        const int row = row0 + mi * 16 + quad * 4 + r;
        C[(size_t)row * DKK + col] = acc[mi * 2 + ni][r];
      }
  }
}

extern "C" void kernel_launch(void* const* d_in, const int* in_sizes, int n_in,
                              void* d_out, int out_size, void* d_ws, size_t ws_size,
                              hipStream_t stream)
{
  char* ws = (char*)d_ws;
  bf16*  W0   = (bf16*)(ws + WS_W(0));
  float* stat = (float*)(ws + WS_ST);
  bf16*  q    = (bf16*)(ws + WS_Q);
  bf16*  kk   = (bf16*)(ws + WS_K);
  bf16*  vT   = (bf16*)(ws + WS_VT);
  unsigned short* Pp = (unsigned short*)(ws + WS_LG);

  const float qscale = 0.044194173824159216f;  // 512^-0.5

  dim3 blk(256, 1, 1);
  // d_in order: qin,kin,vin,Wq,bq,Wk,bk,Wv,bv (all f32)
  hipLaunchKernelGGL(convert_w, dim3(768), blk, 0, stream,
                     (const float*)d_in[3], (const float*)d_in[5],
                     (const float*)d_in[7], ws);
  hipLaunchKernelGGL(proj_kernel, dim3(768, 1, 1), blk, 0, stream,
                     (const float*)d_in[0], (const float*)d_in[1],
                     (const float*)d_in[2], W0,
                     (const float*)d_in[4], (const float*)d_in[6],
                     (const float*)d_in[8], q, kk, vT, qscale);
  hipLaunchKernelGGL(scores_kernel, dim3(16, 16, 8), blk, 0, stream,
                     q, kk, Pp, stat);
  hipLaunchKernelGGL(pv_kernel, dim3(8, 16, 8), blk, 0, stream,
                     Pp, vT, stat, (float*)d_out);
}

// Round 8
// 228.707 us; speedup vs baseline: 1.0074x; 1.0074x over previous
//
#include <hip/hip_runtime.h>
#include <hip/hip_bf16.h>

// Problem: B=8, S=1024, EMBED=1024, DK=DV=512, M=64. Inputs/outputs f32.
// Identity: landmark selection is a segment permutation P of k, so
// kernel_1 = K3 P^T, pinv(kernel_2) = P pinv(K3), and
// out = K3 K3+ K3 v = K3 v == softmax(q k^T) v  (standard attention).
#define SS   1024
#define DKK  512

typedef __hip_bfloat16 bf16;
typedef __attribute__((ext_vector_type(8))) short s16x8;            // 8 x bf16
typedef __attribute__((ext_vector_type(8))) unsigned short u16x8;
typedef __attribute__((ext_vector_type(4))) float f32x4;

// ---- ws layout (byte offsets), 76 MiB ----
// X(z) bf16 16 MiB at 0/16/32 (X0 region reused as P' after proj);
// W(z) bf16 1 MiB at 48+z; stats 1 MiB at 51; q 52; k 60; vT 68.
#define WS_X(z)  ((size_t)(z) << 24)
#define WS_W(z)  ((48ull << 20) + ((size_t)(z) << 20))
#define WS_ST    (51ull << 20)
#define WS_Q     (52ull << 20)
#define WS_K     (60ull << 20)
#define WS_VT    (68ull << 20)
#define WS_LG    (0ull)

__device__ __forceinline__ void async_ld16(const void* g, void* s) {
  __builtin_amdgcn_global_load_lds(
      (const __attribute__((address_space(1))) void*)g,
      (__attribute__((address_space(3))) void*)s, 16, 0, 0);
}

__device__ __forceinline__ unsigned short f2bfu(float f) {
  return __builtin_bit_cast(unsigned short, __float2bfloat16(f));
}
__device__ __forceinline__ float bfu2f(unsigned short u) {
  unsigned int i = ((unsigned int)u) << 16;
  return __builtin_bit_cast(float, i);
}

// Convert 3 X tensors (8M elems) + 3 W tensors (512K) f32 -> bf16 into ws.
// 16 elems/thread; 16 B stores. Grid 6528.
__global__ __launch_bounds__(256)
void convert_all(const float* __restrict__ x0, const float* __restrict__ x1,
                 const float* __restrict__ x2, const float* __restrict__ w0,
                 const float* __restrict__ w1, const float* __restrict__ w2,
                 char* __restrict__ ws)
{
  const int bx = blockIdx.x;
  const float* src; unsigned short* dst; int local;
  if (bx < 6144) {
    const int z = bx >> 11; local = bx & 2047;
    src = (z == 0) ? x0 : (z == 1) ? x1 : x2;
    dst = (unsigned short*)(ws + WS_X(z));
  } else {
    const int t = bx - 6144; const int z = t >> 7; local = t & 127;
    src = (z == 0) ? w0 : (z == 1) ? w1 : w2;
    dst = (unsigned short*)(ws + WS_W(z));
  }
  const int i = local * 4096 + threadIdx.x * 16;
  const float4* s = (const float4*)(src + i);
  float4 a = s[0], b = s[1], c = s[2], d = s[3];
  u16x8 o0, o1;
  o0[0] = f2bfu(a.x); o0[1] = f2bfu(a.y); o0[2] = f2bfu(a.z); o0[3] = f2bfu(a.w);
  o0[4] = f2bfu(b.x); o0[5] = f2bfu(b.y); o0[6] = f2bfu(b.z); o0[7] = f2bfu(b.w);
  o1[0] = f2bfu(c.x); o1[1] = f2bfu(c.y); o1[2] = f2bfu(c.z); o1[3] = f2bfu(c.w);
  o1[4] = f2bfu(d.x); o1[5] = f2bfu(d.y); o1[6] = f2bfu(d.z); o1[7] = f2bfu(d.w);
  *(u16x8*)(dst + i) = o0;
  *(u16x8*)(dst + i + 8) = o1;
}

// ---------- bf16 x bf16 core ----------
// C[BM x BN] = A[BM x K] * B[BN x K]^T, both K-contiguous bf16.
// LDS via global_load_lds w=16; LDS[row][slot] holds chunk (slot ^ (row&7)).
template<int BM, int BN, int K, int LDA, int LDB>
__device__ __forceinline__ void gemm_core(const bf16* __restrict__ A,
                                          const bf16* __restrict__ Bw,
                                          int bm, int bn,
                                          short* As, short* Bs, f32x4* acc)
{
  constexpr int MI = BM / 32, NI = BN / 32;
  constexpr int AR = BM / 4,  BR = BN / 4;
  const int tid  = threadIdx.x;
  const int lane = tid & 63;
  const int wave = tid >> 6;
  const int l8   = lane >> 3;
  const int kch  = ((lane & 7) ^ l8) * 8;
  const bf16* ag = A  + (size_t)(bm * BM + wave * AR + l8) * LDA + kch;
  const bf16* bg = Bw + (size_t)(bn * BN + wave * BR + l8) * LDB + kch;
  short* AsW = As + wave * AR * 64;
  short* BsW = Bs + wave * BR * 64;
  const int waveM = wave >> 1, waveN = wave & 1;
  const int l16  = lane & 15;
  const int quad = lane >> 4;
  const int xr   = l16 & 7;

  #pragma unroll
  for (int t = 0; t < MI * NI; ++t)
    #pragma unroll
    for (int r = 0; r < 4; ++r) acc[t][r] = 0.0f;

  for (int kt = 0; kt < K / 64; ++kt) {
    #pragma unroll
    for (int j = 0; j < AR / 8; ++j) async_ld16(ag + (size_t)j * 8 * LDA, AsW + j * 8 * 64);
    #pragma unroll
    for (int j = 0; j < BR / 8; ++j) async_ld16(bg + (size_t)j * 8 * LDB, BsW + j * 8 * 64);
    ag += 64; bg += 64;
    __syncthreads();
    #pragma unroll
    for (int ks = 0; ks < 2; ++ks) {
      s16x8 af[MI], bfv[NI];
      #pragma unroll
      for (int mi = 0; mi < MI; ++mi) {
        const int row  = waveM * (BM / 2) + mi * 16 + l16;
        const int slot = (ks * 4 + quad) ^ xr;
        af[mi] = *(const s16x8*)&As[row * 64 + slot * 8];
      }
      #pragma unroll
      for (int ni = 0; ni < NI; ++ni) {
        const int row  = waveN * (BN / 2) + ni * 16 + l16;
        const int slot = (ks * 4 + quad) ^ xr;
        bfv[ni] = *(const s16x8*)&Bs[row * 64 + slot * 8];
      }
      #pragma unroll
      for (int mi = 0; mi < MI; ++mi)
        #pragma unroll
        for (int ni = 0; ni < NI; ++ni)
          acc[mi * NI + ni] = __builtin_amdgcn_mfma_f32_16x16x32_bf16(
              af[mi], bfv[ni], acc[mi * NI + ni], 0, 0, 0);
    }
    __syncthreads();
  }
}

// z=0: q = (Xq Wq^T + bq) * 512^-0.5 ; z=1: k = Xk Wk^T + bk ;
// z=2: vT[b][d][s] = (Xv Wv^T + bv)^T.  (R2's measured-41us structure.)
__global__ __launch_bounds__(256, 2)
void proj_kernel(const bf16* __restrict__ X0, const bf16* __restrict__ W0,
                 const float* __restrict__ bq, const float* __restrict__ bk,
                 const float* __restrict__ bv,
                 bf16* __restrict__ qo, bf16* __restrict__ ko,
                 bf16* __restrict__ vT, float qscale)
{
  __shared__ __align__(16) short As[128 * 64];
  __shared__ __align__(16) short Bs[128 * 64];
  const int z = blockIdx.z;
  const bf16* A  = X0 + (size_t)z * 8388608;
  const bf16* Bw = W0 + ((size_t)z << 19);
  const float* bias = (z == 0) ? bq : (z == 1) ? bk : bv;
  f32x4 acc[16];
  gemm_core<128, 128, 1024, 1024, 1024>(A, Bw, blockIdx.x, blockIdx.y, As, Bs, acc);

  const int lane = threadIdx.x & 63;
  const int wave = threadIdx.x >> 6;
  const int waveM = wave >> 1, waveN = wave & 1;
  const int l16 = lane & 15, quad = lane >> 4;
  const int row0 = blockIdx.x * 128 + waveM * 64;
  const int col0 = blockIdx.y * 128 + waveN * 64;
  const float sc = (z == 0) ? qscale : 1.0f;
  bf16* C = (z == 0) ? qo : ko;
  #pragma unroll
  for (int ni = 0; ni < 4; ++ni) {
    const int col = col0 + ni * 16 + l16;
    const float bb = bias[col];
    #pragma unroll
    for (int mi = 0; mi < 4; ++mi)
      #pragma unroll
      for (int r = 0; r < 4; ++r) {
        const int row = row0 + mi * 16 + quad * 4 + r;
        const float v = acc[mi * 4 + ni][r] + bb;
        if (z == 2)
          vT[((size_t)(row >> 10) * DKK + col) * SS + (row & (SS - 1))] =
              __float2bfloat16(v);
        else
          C[(size_t)row * DKK + col] = __float2bfloat16(v * sc);
      }
  }
}

// scores: P'[b][s][t] = bf16(exp(x - m_chunk)), x = q.k, plus per-(row,
// 64-col chunk) stats (m, sum) f32. BM=BN=128, grid (8,8,8) = 512 blocks.
__global__ __launch_bounds__(256, 3)
void scores_kernel(const bf16* __restrict__ q, const bf16* __restrict__ k,
                   unsigned short* __restrict__ Pp, float* __restrict__ stats)
{
  __shared__ __align__(16) short As[128 * 64];
  __shared__ __align__(16) short Bs[128 * 64];
  const int z = blockIdx.z;
  const int bn = blockIdx.x, bm = blockIdx.y;
  f32x4 acc[16];
  gemm_core<128, 128, 512, 512, 512>(q + (size_t)z * SS * DKK,
                                     k + (size_t)z * SS * DKK,
                                     bm, bn, As, Bs, acc);

  const int lane = threadIdx.x & 63;
  const int wave = threadIdx.x >> 6;
  const int waveM = wave >> 1, waveN = wave & 1;
  const int l16 = lane & 15, quad = lane >> 4;
  const int row0 = bm * 128 + waveM * 64;
  const int col0 = bn * 128 + waveN * 64;
  const int chunk = bn * 2 + waveN;             // 64-col chunk id, 0..15
  unsigned short* C = Pp + (size_t)z * SS * SS;
  #pragma unroll
  for (int mi = 0; mi < 4; ++mi)
    #pragma unroll
    for (int r = 0; r < 4; ++r) {
      const int row = row0 + mi * 16 + quad * 4 + r;
      float x[4];
      #pragma unroll
      for (int ni = 0; ni < 4; ++ni) x[ni] = acc[mi * 4 + ni][r];
      float m = fmaxf(fmaxf(x[0], x[1]), fmaxf(x[2], x[3]));
      #pragma unroll
      for (int msk = 1; msk < 16; msk <<= 1) m = fmaxf(m, __shfl_xor(m, msk));
      float e[4], ssum = 0.f;
      #pragma unroll
      for (int ni = 0; ni < 4; ++ni) { e[ni] = __expf(x[ni] - m); ssum += e[ni]; }
      #pragma unroll
      for (int msk = 1; msk < 16; msk <<= 1) ssum += __shfl_xor(ssum, msk);
      #pragma unroll
      for (int ni = 0; ni < 4; ++ni)
        C[(size_t)row * SS + col0 + ni * 16 + l16] = f2bfu(e[ni]);
      if (l16 == 0) {
        float2 mr; mr.x = m; mr.y = ssum;
        *(float2*)&stats[(((size_t)z * SS + row) * 16 + chunk) * 2] = mr;
      }
    }
}

// ---------- pv core: BM=128, BN=64; A = P' scaled by F[row][kt] at staging.
__device__ __forceinline__ void gemm_core_pvF(const unsigned short* __restrict__ Pp,
                                              const bf16* __restrict__ vT,
                                              int bm, int bn, const float* Fl,
                                              short* As, short* Bs, f32x4* acc)
{
  const int tid  = threadIdx.x;
  const int lane = tid & 63;
  const int wave = tid >> 6;
  const int l8   = lane >> 3;
  const int kch  = ((lane & 7) ^ l8) * 8;
  const bf16* bg = vT + (size_t)(bn * 64 + wave * 16 + l8) * 1024 + kch;
  short* BsW = Bs + wave * 16 * 64;
  const int arow = tid >> 3;            // 0..31
  const int ag8  = tid & 7;
  const int slotA = (ag8 ^ (arow & 7)) * 8;
  const unsigned short* ag = Pp + (size_t)(bm * 128 + arow) * 1024 + ag8 * 8;
  const int waveM = wave >> 1, waveN = wave & 1;
  const int l16  = lane & 15;
  const int quad = lane >> 4;
  const int xr   = l16 & 7;

  #pragma unroll
  for (int t = 0; t < 8; ++t)
    #pragma unroll
    for (int r = 0; r < 4; ++r) acc[t][r] = 0.0f;

  for (int kt = 0; kt < 16; ++kt) {
    #pragma unroll
    for (int j = 0; j < 2; ++j) async_ld16(bg + (size_t)j * 8 * 1024, BsW + j * 8 * 64);
    bg += 64;
    #pragma unroll
    for (int p = 0; p < 4; ++p) {
      const int rl = p * 32 + arow;
      u16x8 u = *(const u16x8*)(ag + (size_t)p * 32 * 1024);
      const float f = Fl[rl * 17 + kt];
      u16x8 v;
      #pragma unroll
      for (int j = 0; j < 8; ++j)
        v[j] = f2bfu(bfu2f((unsigned short)u[j]) * f);
      *(u16x8*)&As[rl * 64 + slotA] = v;
    }
    ag += 64;
    __syncthreads();
    #pragma unroll
    for (int ks = 0; ks < 2; ++ks) {
      s16x8 af[4], bfv[2];
      #pragma unroll
      for (int mi = 0; mi < 4; ++mi) {
        const int row  = waveM * 64 + mi * 16 + l16;
        const int slot = (ks * 4 + quad) ^ xr;
        af[mi] = *(const s16x8*)&As[row * 64 + slot * 8];
      }
      #pragma unroll
      for (int ni = 0; ni < 2; ++ni) {
        const int row  = waveN * 32 + ni * 16 + l16;
        const int slot = (ks * 4 + quad) ^ xr;
        bfv[ni] = *(const s16x8*)&Bs[row * 64 + slot * 8];
      }
      #pragma unroll
      for (int mi = 0; mi < 4; ++mi)
        #pragma unroll
        for (int ni = 0; ni < 2; ++ni)
          acc[mi * 2 + ni] = __builtin_amdgcn_mfma_f32_16x16x32_bf16(
              af[mi], bfv[ni], acc[mi * 2 + ni], 0, 0, 0);
    }
    __syncthreads();
  }
}

// out[b][s][d] = softmax(x)[b][s][:] . vT[b][d][:]; f32 out.
// grid (bn=8, bm=8, z=8) = 512 blocks.
__global__ __launch_bounds__(256, 3)
void pv_kernel(const unsigned short* __restrict__ Pp, const bf16* __restrict__ vT,
               const float* __restrict__ stats, float* __restrict__ out)
{
  __shared__ __align__(16) short As[128 * 64];
  __shared__ __align__(16) short Bs[64 * 64];
  __shared__ float Fl[128 * 17];
  const int z = blockIdx.z;
  const int bn = blockIdx.x, bm = blockIdx.y;
  const int tid = threadIdx.x;

  if (tid < 128) {
    const float* st = stats + ((size_t)z * SS + bm * 128 + tid) * 32;
    float mc[16], lc[16];
    float M = -1e30f;
    #pragma unroll
    for (int c = 0; c < 16; ++c) {
      mc[c] = st[c * 2]; lc[c] = st[c * 2 + 1];
      M = fmaxf(M, mc[c]);
    }
    float L = 0.f;
    #pragma unroll
    for (int c = 0; c < 16; ++c) {
      mc[c] = __expf(mc[c] - M);
      L += mc[c] * lc[c];
    }
    const float R = 1.0f / L;
    #pragma unroll
    for (int c = 0; c < 16; ++c) Fl[tid * 17 + c] = mc[c] * R;
  }
  __syncthreads();

  f32x4 acc[8];
  gemm_core_pvF(Pp + (size_t)z * SS * SS, vT + (size_t)z * DKK * SS,
                bm, bn, Fl, As, Bs, acc);

  const int lane = tid & 63;
  const int wave = tid >> 6;
  const int waveM = wave >> 1, waveN = wave & 1;
  const int l16 = lane & 15, quad = lane >> 4;
  const int row0 = bm * 128 + waveM * 64;
  const int col0 = bn * 64 + waveN * 32;
  float* C = out + (size_t)z * SS * DKK;
  #pragma unroll
  for (int ni = 0; ni < 2; ++ni) {
    const int col = col0 + ni * 16 + l16;
    #pragma unroll
    for (int mi = 0; mi < 4; ++mi)
      #pragma unroll
      for (int r = 0; r < 4; ++r) {
        const int row = row0 + mi * 16 + quad * 4 + r;
        C[(size_t)row * DKK + col] = acc[mi * 2 + ni][r];
      }
  }
}

extern "C" void kernel_launch(void* const* d_in, const int* in_sizes, int n_in,
                              void* d_out, int out_size, void* d_ws, size_t ws_size,
                              hipStream_t stream)
{
  char* ws = (char*)d_ws;
  bf16*  X0   = (bf16*)(ws + WS_X(0));
  bf16*  W0   = (bf16*)(ws + WS_W(0));
  float* stat = (float*)(ws + WS_ST);
  bf16*  q    = (bf16*)(ws + WS_Q);
  bf16*  kk   = (bf16*)(ws + WS_K);
  bf16*  vT   = (bf16*)(ws + WS_VT);
  unsigned short* Pp = (unsigned short*)(ws + WS_LG);

  const float qscale = 0.044194173824159216f;  // 512^-0.5

  dim3 blk(256, 1, 1);
  // d_in order: qin,kin,vin,Wq,bq,Wk,bk,Wv,bv (all f32)
  hipLaunchKernelGGL(convert_all, dim3(6528), blk, 0, stream,
                     (const float*)d_in[0], (const float*)d_in[1],
                     (const float*)d_in[2], (const float*)d_in[3],
                     (const float*)d_in[5], (const float*)d_in[7], ws);
  hipLaunchKernelGGL(proj_kernel, dim3(64, 4, 3), blk, 0, stream,
                     X0, W0, (const float*)d_in[4], (const float*)d_in[6],
                     (const float*)d_in[8], q, kk, vT, qscale);
  hipLaunchKernelGGL(scores_kernel, dim3(8, 8, 8), blk, 0, stream,
                     q, kk, Pp, stat);
  hipLaunchKernelGGL(pv_kernel, dim3(8, 8, 8), blk, 0, stream,
                     Pp, vT, stat, (float*)d_out);
}

// Round 9
// 228.348 us; speedup vs baseline: 1.0090x; 1.0016x over previous
//
#include <hip/hip_runtime.h>
#include <hip/hip_bf16.h>

// Problem: B=8, S=1024, EMBED=1024, DK=DV=512, M=64. Inputs/outputs f32.
// Identity: landmark selection is a segment permutation P of k, so
// kernel_1 = K3 P^T, pinv(kernel_2) = P pinv(K3), and
// out = K3 K3+ K3 v = K3 v == softmax(q k^T) v  (standard attention).
#define SS   1024
#define DKK  512

typedef __hip_bfloat16 bf16;
typedef __attribute__((ext_vector_type(8))) short s16x8;            // 8 x bf16
typedef __attribute__((ext_vector_type(8))) unsigned short u16x8;
typedef __attribute__((ext_vector_type(4))) float f32x4;

// ---- ws layout (byte offsets), 76 MiB ----
// X(z) bf16 16 MiB at 0/16/32 (X0 region reused as P' after proj);
// W(z) bf16 1 MiB at 48+z; stats 1 MiB at 51; q 52; k 60; vT 68.
#define WS_X(z)  ((size_t)(z) << 24)
#define WS_W(z)  ((48ull << 20) + ((size_t)(z) << 20))
#define WS_ST    (51ull << 20)
#define WS_Q     (52ull << 20)
#define WS_K     (60ull << 20)
#define WS_VT    (68ull << 20)
#define WS_LG    (0ull)

__device__ __forceinline__ void async_ld16(const void* g, void* s) {
  __builtin_amdgcn_global_load_lds(
      (const __attribute__((address_space(1))) void*)g,
      (__attribute__((address_space(3))) void*)s, 16, 0, 0);
}

__device__ __forceinline__ unsigned short f2bfu(float f) {
  return __builtin_bit_cast(unsigned short, __float2bfloat16(f));
}
__device__ __forceinline__ float bfu2f(unsigned short u) {
  unsigned int i = ((unsigned int)u) << 16;
  return __builtin_bit_cast(float, i);
}

// Convert 3 X tensors (8M elems) + 3 W tensors (512K) f32 -> bf16 into ws.
// COALESCED: lane i handles float4 index (base + i), stepping 256/iter —
// 16 B/lane contiguous loads (1 KB/wave-inst), 8 B/lane contiguous stores.
// Block = 8192 elems (2048 float4s, 8 iters). Grid 3*1024 + 3*64 = 3264.
__global__ __launch_bounds__(256)
void convert_all(const float* __restrict__ x0, const float* __restrict__ x1,
                 const float* __restrict__ x2, const float* __restrict__ w0,
                 const float* __restrict__ w1, const float* __restrict__ w2,
                 char* __restrict__ ws)
{
  const int bx = blockIdx.x;
  const float* src; unsigned short* dst; int local;
  if (bx < 3072) {
    const int z = bx >> 10; local = bx & 1023;
    src = (z == 0) ? x0 : (z == 1) ? x1 : x2;
    dst = (unsigned short*)(ws + WS_X(z));
  } else {
    const int t = bx - 3072; const int z = t >> 6; local = t & 63;
    src = (z == 0) ? w0 : (z == 1) ? w1 : w2;
    dst = (unsigned short*)(ws + WS_W(z));
  }
  const float4* s4 = (const float4*)(src) + local * 2048 + threadIdx.x;
  ushort4* d4 = (ushort4*)(dst) + local * 2048 + threadIdx.x;
  #pragma unroll
  for (int j = 0; j < 8; ++j) {
    float4 a = s4[j * 256];
    ushort4 o;
    o.x = f2bfu(a.x); o.y = f2bfu(a.y); o.z = f2bfu(a.z); o.w = f2bfu(a.w);
    d4[j * 256] = o;
  }
}

// ---------- bf16 x bf16 core ----------
// C[BM x BN] = A[BM x K] * B[BN x K]^T, both K-contiguous bf16.
// LDS via global_load_lds w=16; LDS[row][slot] holds chunk (slot ^ (row&7)).
template<int BM, int BN, int K, int LDA, int LDB>
__device__ __forceinline__ void gemm_core(const bf16* __restrict__ A,
                                          const bf16* __restrict__ Bw,
                                          int bm, int bn,
                                          short* As, short* Bs, f32x4* acc)
{
  constexpr int MI = BM / 32, NI = BN / 32;
  constexpr int AR = BM / 4,  BR = BN / 4;
  const int tid  = threadIdx.x;
  const int lane = tid & 63;
  const int wave = tid >> 6;
  const int l8   = lane >> 3;
  const int kch  = ((lane & 7) ^ l8) * 8;
  const bf16* ag = A  + (size_t)(bm * BM + wave * AR + l8) * LDA + kch;
  const bf16* bg = Bw + (size_t)(bn * BN + wave * BR + l8) * LDB + kch;
  short* AsW = As + wave * AR * 64;
  short* BsW = Bs + wave * BR * 64;
  const int waveM = wave >> 1, waveN = wave & 1;
  const int l16  = lane & 15;
  const int quad = lane >> 4;
  const int xr   = l16 & 7;

  #pragma unroll
  for (int t = 0; t < MI * NI; ++t)
    #pragma unroll
    for (int r = 0; r < 4; ++r) acc[t][r] = 0.0f;

  for (int kt = 0; kt < K / 64; ++kt) {
    #pragma unroll
    for (int j = 0; j < AR / 8; ++j) async_ld16(ag + (size_t)j * 8 * LDA, AsW + j * 8 * 64);
    #pragma unroll
    for (int j = 0; j < BR / 8; ++j) async_ld16(bg + (size_t)j * 8 * LDB, BsW + j * 8 * 64);
    ag += 64; bg += 64;
    __syncthreads();
    #pragma unroll
    for (int ks = 0; ks < 2; ++ks) {
      s16x8 af[MI], bfv[NI];
      #pragma unroll
      for (int mi = 0; mi < MI; ++mi) {
        const int row  = waveM * (BM / 2) + mi * 16 + l16;
        const int slot = (ks * 4 + quad) ^ xr;
        af[mi] = *(const s16x8*)&As[row * 64 + slot * 8];
      }
      #pragma unroll
      for (int ni = 0; ni < NI; ++ni) {
        const int row  = waveN * (BN / 2) + ni * 16 + l16;
        const int slot = (ks * 4 + quad) ^ xr;
        bfv[ni] = *(const s16x8*)&Bs[row * 64 + slot * 8];
      }
      #pragma unroll
      for (int mi = 0; mi < MI; ++mi)
        #pragma unroll
        for (int ni = 0; ni < NI; ++ni)
          acc[mi * NI + ni] = __builtin_amdgcn_mfma_f32_16x16x32_bf16(
              af[mi], bfv[ni], acc[mi * NI + ni], 0, 0, 0);
    }
    __syncthreads();
  }
}

// z=0: q = (Xq Wq^T + bq) * 512^-0.5 ; z=1: k = Xk Wk^T + bk ;
// z=2: vT[b][d][s] = (Xv Wv^T + bv)^T.  (R2's measured-41us structure.)
__global__ __launch_bounds__(256, 2)
void proj_kernel(const bf16* __restrict__ X0, const bf16* __restrict__ W0,
                 const float* __restrict__ bq, const float* __restrict__ bk,
                 const float* __restrict__ bv,
                 bf16* __restrict__ qo, bf16* __restrict__ ko,
                 bf16* __restrict__ vT, float qscale)
{
  __shared__ __align__(16) short As[128 * 64];
  __shared__ __align__(16) short Bs[128 * 64];
  const int z = blockIdx.z;
  const bf16* A  = X0 + (size_t)z * 8388608;
  const bf16* Bw = W0 + ((size_t)z << 19);
  const float* bias = (z == 0) ? bq : (z == 1) ? bk : bv;
  f32x4 acc[16];
  gemm_core<128, 128, 1024, 1024, 1024>(A, Bw, blockIdx.x, blockIdx.y, As, Bs, acc);

  const int lane = threadIdx.x & 63;
  const int wave = threadIdx.x >> 6;
  const int waveM = wave >> 1, waveN = wave & 1;
  const int l16 = lane & 15, quad = lane >> 4;
  const int row0 = blockIdx.x * 128 + waveM * 64;
  const int col0 = blockIdx.y * 128 + waveN * 64;
  const float sc = (z == 0) ? qscale : 1.0f;
  bf16* C = (z == 0) ? qo : ko;
  #pragma unroll
  for (int ni = 0; ni < 4; ++ni) {
    const int col = col0 + ni * 16 + l16;
    const float bb = bias[col];
    #pragma unroll
    for (int mi = 0; mi < 4; ++mi)
      #pragma unroll
      for (int r = 0; r < 4; ++r) {
        const int row = row0 + mi * 16 + quad * 4 + r;
        const float v = acc[mi * 4 + ni][r] + bb;
        if (z == 2)
          vT[((size_t)(row >> 10) * DKK + col) * SS + (row & (SS - 1))] =
              __float2bfloat16(v);
        else
          C[(size_t)row * DKK + col] = __float2bfloat16(v * sc);
      }
  }
}

// scores: P'[b][s][t] = bf16(exp(x - m_chunk)), x = q.k, plus per-(row,
// 64-col chunk) stats (m, sum) f32. BM=BN=128, grid (8,8,8) = 512 blocks.
__global__ __launch_bounds__(256, 3)
void scores_kernel(const bf16* __restrict__ q, const bf16* __restrict__ k,
                   unsigned short* __restrict__ Pp, float* __restrict__ stats)
{
  __shared__ __align__(16) short As[128 * 64];
  __shared__ __align__(16) short Bs[128 * 64];
  const int z = blockIdx.z;
  const int bn = blockIdx.x, bm = blockIdx.y;
  f32x4 acc[16];
  gemm_core<128, 128, 512, 512, 512>(q + (size_t)z * SS * DKK,
                                     k + (size_t)z * SS * DKK,
                                     bm, bn, As, Bs, acc);

  const int lane = threadIdx.x & 63;
  const int wave = threadIdx.x >> 6;
  const int waveM = wave >> 1, waveN = wave & 1;
  const int l16 = lane & 15, quad = lane >> 4;
  const int row0 = bm * 128 + waveM * 64;
  const int col0 = bn * 128 + waveN * 64;
  const int chunk = bn * 2 + waveN;             // 64-col chunk id, 0..15
  unsigned short* C = Pp + (size_t)z * SS * SS;
  #pragma unroll
  for (int mi = 0; mi < 4; ++mi)
    #pragma unroll
    for (int r = 0; r < 4; ++r) {
      const int row = row0 + mi * 16 + quad * 4 + r;
      float x[4];
      #pragma unroll
      for (int ni = 0; ni < 4; ++ni) x[ni] = acc[mi * 4 + ni][r];
      float m = fmaxf(fmaxf(x[0], x[1]), fmaxf(x[2], x[3]));
      #pragma unroll
      for (int msk = 1; msk < 16; msk <<= 1) m = fmaxf(m, __shfl_xor(m, msk));
      float e[4], ssum = 0.f;
      #pragma unroll
      for (int ni = 0; ni < 4; ++ni) { e[ni] = __expf(x[ni] - m); ssum += e[ni]; }
      #pragma unroll
      for (int msk = 1; msk < 16; msk <<= 1) ssum += __shfl_xor(ssum, msk);
      #pragma unroll
      for (int ni = 0; ni < 4; ++ni)
        C[(size_t)row * SS + col0 + ni * 16 + l16] = f2bfu(e[ni]);
      if (l16 == 0) {
        float2 mr; mr.x = m; mr.y = ssum;
        *(float2*)&stats[(((size_t)z * SS + row) * 16 + chunk) * 2] = mr;
      }
    }
}

// ---------- pv core: BM=128, BN=64; A = P' scaled by F[row][kt] at staging.
__device__ __forceinline__ void gemm_core_pvF(const unsigned short* __restrict__ Pp,
                                              const bf16* __restrict__ vT,
                                              int bm, int bn, const float* Fl,
                                              short* As, short* Bs, f32x4* acc)
{
  const int tid  = threadIdx.x;
  const int lane = tid & 63;
  const int wave = tid >> 6;
  const int l8   = lane >> 3;
  const int kch  = ((lane & 7) ^ l8) * 8;
  const bf16* bg = vT + (size_t)(bn * 64 + wave * 16 + l8) * 1024 + kch;
  short* BsW = Bs + wave * 16 * 64;
  const int arow = tid >> 3;            // 0..31
  const int ag8  = tid & 7;
  const int slotA = (ag8 ^ (arow & 7)) * 8;
  const unsigned short* ag = Pp + (size_t)(bm * 128 + arow) * 1024 + ag8 * 8;
  const int waveM = wave >> 1, waveN = wave & 1;
  const int l16  = lane & 15;
  const int quad = lane >> 4;
  const int xr   = l16 & 7;

  #pragma unroll
  for (int t = 0; t < 8; ++t)
    #pragma unroll
    for (int r = 0; r < 4; ++r) acc[t][r] = 0.0f;

  for (int kt = 0; kt < 16; ++kt) {
    #pragma unroll
    for (int j = 0; j < 2; ++j) async_ld16(bg + (size_t)j * 8 * 1024, BsW + j * 8 * 64);
    bg += 64;
    #pragma unroll
    for (int p = 0; p < 4; ++p) {
      const int rl = p * 32 + arow;
      u16x8 u = *(const u16x8*)(ag + (size_t)p * 32 * 1024);
      const float f = Fl[rl * 17 + kt];
      u16x8 v;
      #pragma unroll
      for (int j = 0; j < 8; ++j)
        v[j] = f2bfu(bfu2f((unsigned short)u[j]) * f);
      *(u16x8*)&As[rl * 64 + slotA] = v;
    }
    ag += 64;
    __syncthreads();
    #pragma unroll
    for (int ks = 0; ks < 2; ++ks) {
      s16x8 af[4], bfv[2];
      #pragma unroll
      for (int mi = 0; mi < 4; ++mi) {
        const int row  = waveM * 64 + mi * 16 + l16;
        const int slot = (ks * 4 + quad) ^ xr;
        af[mi] = *(const s16x8*)&As[row * 64 + slot * 8];
      }
      #pragma unroll
      for (int ni = 0; ni < 2; ++ni) {
        const int row  = waveN * 32 + ni * 16 + l16;
        const int slot = (ks * 4 + quad) ^ xr;
        bfv[ni] = *(const s16x8*)&Bs[row * 64 + slot * 8];
      }
      #pragma unroll
      for (int mi = 0; mi < 4; ++mi)
        #pragma unroll
        for (int ni = 0; ni < 2; ++ni)
          acc[mi * 2 + ni] = __builtin_amdgcn_mfma_f32_16x16x32_bf16(
              af[mi], bfv[ni], acc[mi * 2 + ni], 0, 0, 0);
    }
    __syncthreads();
  }
}

// out[b][s][d] = softmax(x)[b][s][:] . vT[b][d][:]; f32 out.
// grid (bn=8, bm=8, z=8) = 512 blocks.
__global__ __launch_bounds__(256, 3)
void pv_kernel(const unsigned short* __restrict__ Pp, const bf16* __restrict__ vT,
               const float* __restrict__ stats, float* __restrict__ out)
{
  __shared__ __align__(16) short As[128 * 64];
  __shared__ __align__(16) short Bs[64 * 64];
  __shared__ float Fl[128 * 17];
  const int z = blockIdx.z;
  const int bn = blockIdx.x, bm = blockIdx.y;
  const int tid = threadIdx.x;

  if (tid < 128) {
    const float* st = stats + ((size_t)z * SS + bm * 128 + tid) * 32;
    float mc[16], lc[16];
    float M = -1e30f;
    #pragma unroll
    for (int c = 0; c < 16; ++c) {
      mc[c] = st[c * 2]; lc[c] = st[c * 2 + 1];
      M = fmaxf(M, mc[c]);
    }
    float L = 0.f;
    #pragma unroll
    for (int c = 0; c < 16; ++c) {
      mc[c] = __expf(mc[c] - M);
      L += mc[c] * lc[c];
    }
    const float R = 1.0f / L;
    #pragma unroll
    for (int c = 0; c < 16; ++c) Fl[tid * 17 + c] = mc[c] * R;
  }
  __syncthreads();

  f32x4 acc[8];
  gemm_core_pvF(Pp + (size_t)z * SS * SS, vT + (size_t)z * DKK * SS,
                bm, bn, Fl, As, Bs, acc);

  const int lane = tid & 63;
  const int wave = tid >> 6;
  const int waveM = wave >> 1, waveN = wave & 1;
  const int l16 = lane & 15, quad = lane >> 4;
  const int row0 = bm * 128 + waveM * 64;
  const int col0 = bn * 64 + waveN * 32;
  float* C = out + (size_t)z * SS * DKK;
  #pragma unroll
  for (int ni = 0; ni < 2; ++ni) {
    const int col = col0 + ni * 16 + l16;
    #pragma unroll
    for (int mi = 0; mi < 4; ++mi)
      #pragma unroll
      for (int r = 0; r < 4; ++r) {
        const int row = row0 + mi * 16 + quad * 4 + r;
        C[(size_t)row * DKK + col] = acc[mi * 2 + ni][r];
      }
  }
}

extern "C" void kernel_launch(void* const* d_in, const int* in_sizes, int n_in,
                              void* d_out, int out_size, void* d_ws, size_t ws_size,
                              hipStream_t stream)
{
  char* ws = (char*)d_ws;
  bf16*  X0   = (bf16*)(ws + WS_X(0));
  bf16*  W0   = (bf16*)(ws + WS_W(0));
  float* stat = (float*)(ws + WS_ST);
  bf16*  q    = (bf16*)(ws + WS_Q);
  bf16*  kk   = (bf16*)(ws + WS_K);
  bf16*  vT   = (bf16*)(ws + WS_VT);
  unsigned short* Pp = (unsigned short*)(ws + WS_LG);

  const float qscale = 0.044194173824159216f;  // 512^-0.5

  dim3 blk(256, 1, 1);
  // d_in order: qin,kin,vin,Wq,bq,Wk,bk,Wv,bv (all f32)
  hipLaunchKernelGGL(convert_all, dim3(3264), blk, 0, stream,
                     (const float*)d_in[0], (const float*)d_in[1],
                     (const float*)d_in[2], (const float*)d_in[3],
                     (const float*)d_in[5], (const float*)d_in[7], ws);
  hipLaunchKernelGGL(proj_kernel, dim3(64, 4, 3), blk, 0, stream,
                     X0, W0, (const float*)d_in[4], (const float*)d_in[6],
                     (const float*)d_in[8], q, kk, vT, qscale);
  hipLaunchKernelGGL(scores_kernel, dim3(8, 8, 8), blk, 0, stream,
                     q, kk, Pp, stat);
  hipLaunchKernelGGL(pv_kernel, dim3(8, 8, 8), blk, 0, stream,
                     Pp, vT, stat, (float*)d_out);
}

// Round 10
// 221.768 us; speedup vs baseline: 1.0390x; 1.0297x over previous
//
#include <hip/hip_runtime.h>
#include <hip/hip_bf16.h>

// Problem: B=8, S=1024, EMBED=1024, DK=DV=512, M=64. Inputs/outputs f32.
// Identity: landmark selection is a segment permutation P of k, so
// kernel_1 = K3 P^T, pinv(kernel_2) = P pinv(K3), and
// out = K3 K3+ K3 v = K3 v == softmax(q k^T) v  (standard attention).
#define SS   1024
#define DKK  512

typedef __hip_bfloat16 bf16;
typedef __attribute__((ext_vector_type(8))) short s16x8;            // 8 x bf16
typedef __attribute__((ext_vector_type(8))) unsigned short u16x8;
typedef __attribute__((ext_vector_type(4))) float f32x4;

// ---- ws layout (byte offsets), 76 MiB ----
// P' 16 MiB at 0; W(z) bf16 1 MiB at 48+z; stats 1 MiB at 51; q 52; k 60; vT 68.
#define WS_W(z)  ((48ull << 20) + ((size_t)(z) << 20))
#define WS_ST    (51ull << 20)
#define WS_Q     (52ull << 20)
#define WS_K     (60ull << 20)
#define WS_VT    (68ull << 20)
#define WS_LG    (0ull)

__device__ __forceinline__ void async_ld16(const void* g, void* s) {
  __builtin_amdgcn_global_load_lds(
      (const __attribute__((address_space(1))) void*)g,
      (__attribute__((address_space(3))) void*)s, 16, 0, 0);
}

__device__ __forceinline__ unsigned short f2bfu(float f) {
  return __builtin_bit_cast(unsigned short, __float2bfloat16(f));
}
__device__ __forceinline__ float bfu2f(unsigned short u) {
  unsigned int i = ((unsigned int)u) << 16;
  return __builtin_bit_cast(float, i);
}

// Convert the 3 weight tensors (512K elems each) f32 -> bf16 into ws.
__global__ __launch_bounds__(256)
void convert_w(const float* __restrict__ w0, const float* __restrict__ w1,
               const float* __restrict__ w2, char* __restrict__ ws)
{
  const int bx = blockIdx.x;
  const int z = bx >> 8, local = bx & 255;
  const float* src = (z == 0) ? w0 : (z == 1) ? w1 : w2;
  unsigned short* dst = (unsigned short*)(ws + WS_W(z));
  const int i = local * 2048 + threadIdx.x * 8;
  const float4* s = (const float4*)(src + i);
  float4 a = s[0], b = s[1];
  ushort4 o0, o1;
  o0.x = f2bfu(a.x); o0.y = f2bfu(a.y); o0.z = f2bfu(a.z); o0.w = f2bfu(a.w);
  o1.x = f2bfu(b.x); o1.y = f2bfu(b.y); o1.z = f2bfu(b.z); o1.w = f2bfu(b.w);
  ((ushort4*)(dst + i))[0] = o0;
  ((ushort4*)(dst + i))[1] = o1;
}

// ---------- bf16 x bf16 core (scores) ----------
// C[BM x BN] = A[BM x K] * B[BN x K]^T, both K-contiguous bf16.
// LDS via global_load_lds w=16; LDS[row][slot] holds chunk (slot ^ (row&7)).
template<int BM, int BN, int K, int LDA, int LDB>
__device__ __forceinline__ void gemm_core(const bf16* __restrict__ A,
                                          const bf16* __restrict__ Bw,
                                          int bm, int bn,
                                          short* As, short* Bs, f32x4* acc)
{
  constexpr int MI = BM / 32, NI = BN / 32;
  constexpr int AR = BM / 4,  BR = BN / 4;
  const int tid  = threadIdx.x;
  const int lane = tid & 63;
  const int wave = tid >> 6;
  const int l8   = lane >> 3;
  const int kch  = ((lane & 7) ^ l8) * 8;
  const bf16* ag = A  + (size_t)(bm * BM + wave * AR + l8) * LDA + kch;
  const bf16* bg = Bw + (size_t)(bn * BN + wave * BR + l8) * LDB + kch;
  short* AsW = As + wave * AR * 64;
  short* BsW = Bs + wave * BR * 64;
  const int waveM = wave >> 1, waveN = wave & 1;
  const int l16  = lane & 15;
  const int quad = lane >> 4;
  const int xr   = l16 & 7;

  #pragma unroll
  for (int t = 0; t < MI * NI; ++t)
    #pragma unroll
    for (int r = 0; r < 4; ++r) acc[t][r] = 0.0f;

  for (int kt = 0; kt < K / 64; ++kt) {
    #pragma unroll
    for (int j = 0; j < AR / 8; ++j) async_ld16(ag + (size_t)j * 8 * LDA, AsW + j * 8 * 64);
    #pragma unroll
    for (int j = 0; j < BR / 8; ++j) async_ld16(bg + (size_t)j * 8 * LDB, BsW + j * 8 * 64);
    ag += 64; bg += 64;
    __syncthreads();
    #pragma unroll
    for (int ks = 0; ks < 2; ++ks) {
      s16x8 af[MI], bfv[NI];
      #pragma unroll
      for (int mi = 0; mi < MI; ++mi) {
        const int row  = waveM * (BM / 2) + mi * 16 + l16;
        const int slot = (ks * 4 + quad) ^ xr;
        af[mi] = *(const s16x8*)&As[row * 64 + slot * 8];
      }
      #pragma unroll
      for (int ni = 0; ni < NI; ++ni) {
        const int row  = waveN * (BN / 2) + ni * 16 + l16;
        const int slot = (ks * 4 + quad) ^ xr;
        bfv[ni] = *(const s16x8*)&Bs[row * 64 + slot * 8];
      }
      #pragma unroll
      for (int mi = 0; mi < MI; ++mi)
        #pragma unroll
        for (int ni = 0; ni < NI; ++ni)
          acc[mi * NI + ni] = __builtin_amdgcn_mfma_f32_16x16x32_bf16(
              af[mi], bfv[ni], acc[mi * NI + ni], 0, 0, 0);
    }
    __syncthreads();
  }
}

// ---------- f32-A x bf16-B core for proj: BM=64, BN=256 (R6 verbatim) ----
// A f32 staged via reg round-trip + inline cvt into swizzled LDS;
// B bf16 on the async global_load_lds path. Wave tile 32x128.
template<int K, int LDA, int LDB>
__device__ __forceinline__ void gemm_core_f32a(const float* __restrict__ A,
                                               const bf16* __restrict__ Bw,
                                               int bm, int bn,
                                               short* As, short* Bs, f32x4* acc)
{
  const int tid  = threadIdx.x;
  const int lane = tid & 63;
  const int wave = tid >> 6;
  const int l8   = lane >> 3;
  const int kch  = ((lane & 7) ^ l8) * 8;
  const bf16* bg = Bw + (size_t)(bn * 256 + wave * 64 + l8) * LDB + kch;
  short* BsW = Bs + wave * 64 * 64;
  const int arow = tid >> 3;
  const int ag8  = tid & 7;
  const int slotA = (ag8 ^ (arow & 7)) * 8;
  const float* ag = A + (size_t)(bm * 64 + arow) * LDA + ag8 * 8;
  const int waveM = wave >> 1, waveN = wave & 1;
  const int l16  = lane & 15;
  const int quad = lane >> 4;
  const int xr   = l16 & 7;

  #pragma unroll
  for (int t = 0; t < 16; ++t)
    #pragma unroll
    for (int r = 0; r < 4; ++r) acc[t][r] = 0.0f;

  for (int kt = 0; kt < K / 64; ++kt) {
    #pragma unroll
    for (int j = 0; j < 8; ++j) async_ld16(bg + (size_t)j * 8 * LDB, BsW + j * 8 * 64);
    bg += 64;
    #pragma unroll
    for (int p = 0; p < 2; ++p) {
      const float4* s = (const float4*)(ag + (size_t)p * 32 * LDA);
      float4 a = s[0], b = s[1];
      u16x8 v;
      v[0] = f2bfu(a.x); v[1] = f2bfu(a.y); v[2] = f2bfu(a.z); v[3] = f2bfu(a.w);
      v[4] = f2bfu(b.x); v[5] = f2bfu(b.y); v[6] = f2bfu(b.z); v[7] = f2bfu(b.w);
      *(u16x8*)&As[(p * 32 + arow) * 64 + slotA] = v;
    }
    ag += 64;
    __syncthreads();
    #pragma unroll
    for (int ks = 0; ks < 2; ++ks) {
      s16x8 af[2], bfv[8];
      #pragma unroll
      for (int mi = 0; mi < 2; ++mi) {
        const int row  = waveM * 32 + mi * 16 + l16;
        const int slot = (ks * 4 + quad) ^ xr;
        af[mi] = *(const s16x8*)&As[row * 64 + slot * 8];
      }
      #pragma unroll
      for (int ni = 0; ni < 8; ++ni) {
        const int row  = waveN * 128 + ni * 16 + l16;
        const int slot = (ks * 4 + quad) ^ xr;
        bfv[ni] = *(const s16x8*)&Bs[row * 64 + slot * 8];
      }
      #pragma unroll
      for (int mi = 0; mi < 2; ++mi)
        #pragma unroll
        for (int ni = 0; ni < 8; ++ni)
          acc[mi * 8 + ni] = __builtin_amdgcn_mfma_f32_16x16x32_bf16(
              af[mi], bfv[ni], acc[mi * 8 + ni], 0, 0, 0);
    }
    __syncthreads();
  }
}

// z=0: q = (Xq Wq^T + bq) * 512^-0.5 ; z=1: k = Xk Wk^T + bk ;
// z=2: vT[b][d][s] = (Xv Wv^T + bv)^T.
// Flat 768-block grid; bn-siblings of each (bm,z) panel land on one XCD.
__global__ __launch_bounds__(256, 3)
void proj_kernel(const float* __restrict__ Xq, const float* __restrict__ Xk,
                 const float* __restrict__ Xv, const bf16* __restrict__ W0,
                 const float* __restrict__ bq, const float* __restrict__ bk,
                 const float* __restrict__ bv,
                 bf16* __restrict__ qo, bf16* __restrict__ ko,
                 bf16* __restrict__ vT, float qscale)
{
  __shared__ __align__(16) short As[64 * 64];
  __shared__ __align__(16) short Bs[256 * 64];
  const int id   = blockIdx.x;
  const int xcd  = id & 7;
  const int s    = id >> 3;            // 0..95
  const int bn   = s & 1;
  const int pair = (s >> 1) * 8 + xcd; // 0..383 unique
  const int bm   = pair & 127;
  const int z    = pair >> 7;          // 0..2
  const float* A  = (z == 0) ? Xq : (z == 1) ? Xk : Xv;
  const bf16*  Bw = W0 + ((size_t)z << 19);
  const float* bias = (z == 0) ? bq : (z == 1) ? bk : bv;
  f32x4 acc[16];
  gemm_core_f32a<1024, 1024, 1024>(A, Bw, bm, bn, As, Bs, acc);

  const int lane = threadIdx.x & 63;
  const int wave = threadIdx.x >> 6;
  const int waveM = wave >> 1, waveN = wave & 1;
  const int l16 = lane & 15, quad = lane >> 4;
  const int row0 = bm * 64 + waveM * 32;
  const int col0 = bn * 256 + waveN * 128;
  const float sc = (z == 0) ? qscale : 1.0f;
  bf16* C = (z == 0) ? qo : ko;
  #pragma unroll
  for (int ni = 0; ni < 8; ++ni) {
    const int col = col0 + ni * 16 + l16;
    const float bb = bias[col];
    #pragma unroll
    for (int mi = 0; mi < 2; ++mi)
      #pragma unroll
      for (int r = 0; r < 4; ++r) {
        const int row = row0 + mi * 16 + quad * 4 + r;
        const float v = acc[mi * 8 + ni][r] + bb;
        if (z == 2)
          vT[((size_t)(row >> 10) * DKK + col) * SS + (row & (SS - 1))] =
              __float2bfloat16(v);
        else
          C[(size_t)row * DKK + col] = __float2bfloat16(v * sc);
      }
  }
}

// scores: P'[b][s][t] = bf16(exp(x - m_chunk)), x = q.k, plus per-(row,
// 64-col chunk) stats (m, sum) f32. BM=BN=128, grid (8,8,8) = 512 blocks.
__global__ __launch_bounds__(256, 3)
void scores_kernel(const bf16* __restrict__ q, const bf16* __restrict__ k,
                   unsigned short* __restrict__ Pp, float* __restrict__ stats)
{
  __shared__ __align__(16) short As[128 * 64];
  __shared__ __align__(16) short Bs[128 * 64];
  const int z = blockIdx.z;
  const int bn = blockIdx.x, bm = blockIdx.y;
  f32x4 acc[16];
  gemm_core<128, 128, 512, 512, 512>(q + (size_t)z * SS * DKK,
                                     k + (size_t)z * SS * DKK,
                                     bm, bn, As, Bs, acc);

  const int lane = threadIdx.x & 63;
  const int wave = threadIdx.x >> 6;
  const int waveM = wave >> 1, waveN = wave & 1;
  const int l16 = lane & 15, quad = lane >> 4;
  const int row0 = bm * 128 + waveM * 64;
  const int col0 = bn * 128 + waveN * 64;
  const int chunk = bn * 2 + waveN;             // 64-col chunk id, 0..15
  unsigned short* C = Pp + (size_t)z * SS * SS;
  #pragma unroll
  for (int mi = 0; mi < 4; ++mi)
    #pragma unroll
    for (int r = 0; r < 4; ++r) {
      const int row = row0 + mi * 16 + quad * 4 + r;
      float x[4];
      #pragma unroll
      for (int ni = 0; ni < 4; ++ni) x[ni] = acc[mi * 4 + ni][r];
      float m = fmaxf(fmaxf(x[0], x[1]), fmaxf(x[2], x[3]));
      #pragma unroll
      for (int msk = 1; msk < 16; msk <<= 1) m = fmaxf(m, __shfl_xor(m, msk));
      float e[4], ssum = 0.f;
      #pragma unroll
      for (int ni = 0; ni < 4; ++ni) { e[ni] = __expf(x[ni] - m); ssum += e[ni]; }
      #pragma unroll
      for (int msk = 1; msk < 16; msk <<= 1) ssum += __shfl_xor(ssum, msk);
      #pragma unroll
      for (int ni = 0; ni < 4; ++ni)
        C[(size_t)row * SS + col0 + ni * 16 + l16] = f2bfu(e[ni]);
      if (l16 == 0) {
        float2 mr; mr.x = m; mr.y = ssum;
        *(float2*)&stats[(((size_t)z * SS + row) * 16 + chunk) * 2] = mr;
      }
    }
}

// ---------- pv core: BM=128, BN=64; A = P' scaled by F[row][kt] at staging.
__device__ __forceinline__ void gemm_core_pvF(const unsigned short* __restrict__ Pp,
                                              const bf16* __restrict__ vT,
                                              int bm, int bn, const float* Fl,
                                              short* As, short* Bs, f32x4* acc)
{
  const int tid  = threadIdx.x;
  const int lane = tid & 63;
  const int wave = tid >> 6;
  const int l8   = lane >> 3;
  const int kch  = ((lane & 7) ^ l8) * 8;
  const bf16* bg = vT + (size_t)(bn * 64 + wave * 16 + l8) * 1024 + kch;
  short* BsW = Bs + wave * 16 * 64;
  const int arow = tid >> 3;            // 0..31
  const int ag8  = tid & 7;
  const int slotA = (ag8 ^ (arow & 7)) * 8;
  const unsigned short* ag = Pp + (size_t)(bm * 128 + arow) * 1024 + ag8 * 8;
  const int waveM = wave >> 1, waveN = wave & 1;
  const int l16  = lane & 15;
  const int quad = lane >> 4;
  const int xr   = l16 & 7;

  #pragma unroll
  for (int t = 0; t < 8; ++t)
    #pragma unroll
    for (int r = 0; r < 4; ++r) acc[t][r] = 0.0f;

  for (int kt = 0; kt < 16; ++kt) {
    #pragma unroll
    for (int j = 0; j < 2; ++j) async_ld16(bg + (size_t)j * 8 * 1024, BsW + j * 8 * 64);
    bg += 64;
    #pragma unroll
    for (int p = 0; p < 4; ++p) {
      const int rl = p * 32 + arow;
      u16x8 u = *(const u16x8*)(ag + (size_t)p * 32 * 1024);
      const float f = Fl[rl * 17 + kt];
      u16x8 v;
      #pragma unroll
      for (int j = 0; j < 8; ++j)
        v[j] = f2bfu(bfu2f((unsigned short)u[j]) * f);
      *(u16x8*)&As[rl * 64 + slotA] = v;
    }
    ag += 64;
    __syncthreads();
    #pragma unroll
    for (int ks = 0; ks < 2; ++ks) {
      s16x8 af[4], bfv[2];
      #pragma unroll
      for (int mi = 0; mi < 4; ++mi) {
        const int row  = waveM * 64 + mi * 16 + l16;
        const int slot = (ks * 4 + quad) ^ xr;
        af[mi] = *(const s16x8*)&As[row * 64 + slot * 8];
      }
      #pragma unroll
      for (int ni = 0; ni < 2; ++ni) {
        const int row  = waveN * 32 + ni * 16 + l16;
        const int slot = (ks * 4 + quad) ^ xr;
        bfv[ni] = *(const s16x8*)&Bs[row * 64 + slot * 8];
      }
      #pragma unroll
      for (int mi = 0; mi < 4; ++mi)
        #pragma unroll
        for (int ni = 0; ni < 2; ++ni)
          acc[mi * 2 + ni] = __builtin_amdgcn_mfma_f32_16x16x32_bf16(
              af[mi], bfv[ni], acc[mi * 2 + ni], 0, 0, 0);
    }
    __syncthreads();
  }
}

// out[b][s][d] = softmax(x)[b][s][:] . vT[b][d][:]; f32 out.
// grid (bn=8, bm=8, z=8) = 512 blocks.
__global__ __launch_bounds__(256, 3)
void pv_kernel(const unsigned short* __restrict__ Pp, const bf16* __restrict__ vT,
               const float* __restrict__ stats, float* __restrict__ out)
{
  __shared__ __align__(16) short As[128 * 64];
  __shared__ __align__(16) short Bs[64 * 64];
  __shared__ float Fl[128 * 17];
  const int z = blockIdx.z;
  const int bn = blockIdx.x, bm = blockIdx.y;
  const int tid = threadIdx.x;

  if (tid < 128) {
    const float* st = stats + ((size_t)z * SS + bm * 128 + tid) * 32;
    float mc[16], lc[16];
    float M = -1e30f;
    #pragma unroll
    for (int c = 0; c < 16; ++c) {
      mc[c] = st[c * 2]; lc[c] = st[c * 2 + 1];
      M = fmaxf(M, mc[c]);
    }
    float L = 0.f;
    #pragma unroll
    for (int c = 0; c < 16; ++c) {
      mc[c] = __expf(mc[c] - M);
      L += mc[c] * lc[c];
    }
    const float R = 1.0f / L;
    #pragma unroll
    for (int c = 0; c < 16; ++c) Fl[tid * 17 + c] = mc[c] * R;
  }
  __syncthreads();

  f32x4 acc[8];
  gemm_core_pvF(Pp + (size_t)z * SS * SS, vT + (size_t)z * DKK * SS,
                bm, bn, Fl, As, Bs, acc);

  const int lane = tid & 63;
  const int wave = tid >> 6;
  const int waveM = wave >> 1, waveN = wave & 1;
  const int l16 = lane & 15, quad = lane >> 4;
  const int row0 = bm * 128 + waveM * 64;
  const int col0 = bn * 64 + waveN * 32;
  float* C = out + (size_t)z * SS * DKK;
  #pragma unroll
  for (int ni = 0; ni < 2; ++ni) {
    const int col = col0 + ni * 16 + l16;
    #pragma unroll
    for (int mi = 0; mi < 4; ++mi)
      #pragma unroll
      for (int r = 0; r < 4; ++r) {
        const int row = row0 + mi * 16 + quad * 4 + r;
        C[(size_t)row * DKK + col] = acc[mi * 2 + ni][r];
      }
  }
}

extern "C" void kernel_launch(void* const* d_in, const int* in_sizes, int n_in,
                              void* d_out, int out_size, void* d_ws, size_t ws_size,
                              hipStream_t stream)
{
  char* ws = (char*)d_ws;
  bf16*  W0   = (bf16*)(ws + WS_W(0));
  float* stat = (float*)(ws + WS_ST);
  bf16*  q    = (bf16*)(ws + WS_Q);
  bf16*  kk   = (bf16*)(ws + WS_K);
  bf16*  vT   = (bf16*)(ws + WS_VT);
  unsigned short* Pp = (unsigned short*)(ws + WS_LG);

  const float qscale = 0.044194173824159216f;  // 512^-0.5

  dim3 blk(256, 1, 1);
  // d_in order: qin,kin,vin,Wq,bq,Wk,bk,Wv,bv (all f32)
  hipLaunchKernelGGL(convert_w, dim3(768), blk, 0, stream,
                     (const float*)d_in[3], (const float*)d_in[5],
                     (const float*)d_in[7], ws);
  hipLaunchKernelGGL(proj_kernel, dim3(768, 1, 1), blk, 0, stream,
                     (const float*)d_in[0], (const float*)d_in[1],
                     (const float*)d_in[2], W0,
                     (const float*)d_in[4], (const float*)d_in[6],
                     (const float*)d_in[8], q, kk, vT, qscale);
  hipLaunchKernelGGL(scores_kernel, dim3(8, 8, 8), blk, 0, stream,
                     q, kk, Pp, stat);
  hipLaunchKernelGGL(pv_kernel, dim3(8, 8, 8), blk, 0, stream,
                     Pp, vT, stat, (float*)d_out);
}